// Round 6
// baseline (200.168 us; speedup 1.0000x reference)
//
#include <hip/hip_runtime.h>

namespace {
constexpr int Bn = 8, Cn = 256, Hn = 64, Wn = 64;
constexpr int Kk = 5, PAD = 2, KMC = 100, KK2 = 25;  // KMC = UP^2*K^2
constexpr int CSPLIT = 2;                   // channel-split blocks per (b,h)
constexpr int CPB = Cn / CSPLIT;            // 128 channels per block
constexpr int NCB = CPB / 16;               // 8 channel-group iterations
constexpr int NWG = Hn * Bn * CSPLIT;       // 1024 workgroups (4-wave)
constexpr int NXCD = 8;
constexpr int CHUNK = NWG / NXCD;           // 128 consecutive origs per XCD
constexpr int HW = Hn * Wn;                 // 4096
}

// Round 6: WEIGHTS IN LDS. Rounds 0/3/4/5 all reported VGPR 108-112 <
// the ~135 needed to hold wreg[100]+acc[16]+addressing -> the compiler was
// silently re-loading km from global inside the channel loop (L2 hits,
// invisible in FETCH_SIZE), ~100 VMEM loads x ~300cy per iteration = the
// invariant ~6k-cycle/iter stall behind VALUBusy~18% at every schedule.
// Fix: stage all 100x64 weights once into block-shared LDS (all 4 waves
// share (b,h) => share the tile); per-tap reads are lane-contiguous
// ds_read_b32 (2 lanes/bank = conflict-free). Per-thread state ~60 VGPR.
// Keep R4's verified async staging: global_load_lds double-buffer,
// counted vmcnt (never 0 in steady state), wave-private xs, no in-loop
// barriers, XCD-chunked swizzle (FETCH 86.8->23.8 MB).
//
// __launch_bounds__ 2nd arg MUST stay 2: declaring 4 caps VGPRs at 64 ->
// scratch spills (rounds 1-2, 2x slower).
__global__ __launch_bounds__(256, 2) void carafe_fwd(
    const float* __restrict__ x,    // [B, C, H, W]
    const float* __restrict__ km,   // [B, 100, H, W]
    float* __restrict__ out)        // [B, C, 2H, 2W]
{
    // XCD-chunked swizzle: orig = cz + 2*(h + 64*b); h-neighbours and the
    // cz pair are chunk-local -> one XCD's L2 serves x-row + km reuse.
    const int wg   = blockIdx.x;
    const int orig = (wg & (NXCD - 1)) * CHUNK + (wg >> 3);
    const int cz   = orig & 1;
    const int h    = (orig >> 1) & (Hn - 1);
    const int b    = orig >> 7;

    const int tid = threadIdx.x;
    const int wv  = tid >> 6;
    const int w   = tid & 63;

    // double-buffered wave-private staging: [wave][buf][row][col][ch]
    __shared__ __align__(16) float xs[4][2][Kk][68][4];
    // block-shared reassembly weights: kw[t][u][w] = km[b][u*25+t][h][w]
    __shared__ float kw[KK2][4][64];
    __shared__ float dummy[64];   // discard target for out-of-range rows

    // zero xs once: invalid rows + halo cols stay zero forever (DMA only
    // ever writes cols 2..65 of valid rows)
    {
        float* slab = &xs[0][0][0][0][0];
        for (int i = tid; i < 4 * 2 * Kk * 68 * 4; i += 256) slab[i] = 0.0f;
    }

    // cooperative one-time weight staging (coalesced 256B per wave-load)
    {
        const float* kmb = km + ((size_t)b * KMC) * HW + h * Wn;
        for (int idx = tid; idx < KMC * 64; idx += 256) {
            const int ch = idx >> 6;          // 0..99 = u*25 + t
            const int ww = idx & 63;
            const int u  = ch / KK2;
            const int t  = ch - u * KK2;
            kw[t][u][ww] = kmb[(size_t)ch * HW + ww];
        }
    }

    __syncthreads();  // kw + xs zeros visible; drains all VMEM (prologue
                      // STAGE not yet issued, so loop vmcnt counts stay exact)

    const float* xb = x + (size_t)b * Cn * HW;
    float* ob       = out + (size_t)b * Cn * (2 * Hn) * (2 * Wn);

    // staging lane split: lane l -> channel (l&3), col (l>>2) of a 16-col
    // chunk; LDS dest = chunk_base + lane*4 in the [col][ch] layout.
    const int sl_ch = w & 3;
    const int sl_cl = w >> 2;

    // Always exactly 20 global_load_lds (uniform vmcnt bookkeeping):
    // out-of-range rows load a clamped address into the dummy slot.
    auto STAGE = [&](int bi, int c0s) {
        #pragma unroll
        for (int r = 0; r < Kk; ++r) {
            const int hr  = h - PAD + r;
            const int hrc = hr < 0 ? 0 : (hr >= Hn ? Hn - 1 : hr);
            const bool valid = (hr == hrc);                 // wave-uniform
            const float* srow =
                xb + (size_t)(c0s + sl_ch) * HW + hrc * Wn + sl_cl;
            #pragma unroll
            for (int q = 0; q < 4; ++q) {
                float* d = valid ? &xs[wv][bi][r][2 + 16 * q][0] : &dummy[0];
                __builtin_amdgcn_global_load_lds(
                    (const __attribute__((address_space(1))) void*)(srow + 16 * q),
                    (__attribute__((address_space(3))) void*)d, 4, 0, 0);
            }
        }
    };

    STAGE(0, cz * CPB + wv * 4);   // prologue: fill buffer 0

    #pragma unroll 1
    for (int cb = 0; cb < NCB; ++cb) {
        const int c0 = cz * CPB + cb * 16 + wv * 4;

        if (cb + 1 < NCB)
            STAGE((cb + 1) & 1, c0 + 16);   // async prefetch next group

        // Wait for THIS buffer's 20 loads; newer in-flight VMEM ops:
        //   cb==0      : STAGE_1 (20)                        -> vmcnt(20)
        //   0<cb<NCB-1 : stores_{cb-1} (8) + STAGE_{cb+1}(20) -> vmcnt(28)
        //   cb==NCB-1  : stores_{cb-1} (8)                   -> vmcnt(8)
        if (cb == 0)            asm volatile("s_waitcnt vmcnt(20)" ::: "memory");
        else if (cb + 1 < NCB)  asm volatile("s_waitcnt vmcnt(28)" ::: "memory");
        else                    asm volatile("s_waitcnt vmcnt(8)"  ::: "memory");

        const int bi = cb & 1;
        float acc[4][4] = {};  // [channel k][subpixel u]
        #pragma unroll
        for (int kh = 0; kh < Kk; ++kh) {
            #pragma unroll
            for (int kwi = 0; kwi < Kk; ++kwi) {
                const int t = kh * Kk + kwi;
                const float4 tap = *(const float4*)(&xs[wv][bi][kh][w + kwi][0]);
                const float w0 = kw[t][0][w];
                const float w1 = kw[t][1][w];
                const float w2 = kw[t][2][w];
                const float w3 = kw[t][3][w];
                acc[0][0] += tap.x * w0; acc[0][1] += tap.x * w1;
                acc[0][2] += tap.x * w2; acc[0][3] += tap.x * w3;
                acc[1][0] += tap.y * w0; acc[1][1] += tap.y * w1;
                acc[1][2] += tap.y * w2; acc[1][3] += tap.y * w3;
                acc[2][0] += tap.z * w0; acc[2][1] += tap.z * w1;
                acc[2][2] += tap.z * w2; acc[2][3] += tap.z * w3;
                acc[3][0] += tap.w * w0; acc[3][1] += tap.w * w1;
                acc[3][2] += tap.w * w2; acc[3][3] += tap.w * w3;
            }
        }

        // out[b, c0+k, 2h+i, 2w+j]; 8 global_store_dwordx2 per iteration,
        // lane-consecutive -> 512B contiguous per store
        #pragma unroll
        for (int k = 0; k < 4; ++k) {
            #pragma unroll
            for (int i = 0; i < 2; ++i) {
                float2 o2 = make_float2(acc[k][2 * i + 0], acc[k][2 * i + 1]);
                *(float2*)(&ob[((size_t)(c0 + k) * (2 * Hn) + (2 * h + i)) *
                                   (2 * Wn) + 2 * w]) = o2;
            }
        }
    }
}

extern "C" void kernel_launch(void* const* d_in, const int* in_sizes, int n_in,
                              void* d_out, int out_size, void* d_ws, size_t ws_size,
                              hipStream_t stream)
{
    const float* x  = (const float*)d_in[0];
    const float* km = (const float*)d_in[1];
    float* out      = (float*)d_out;

    dim3 grid(NWG);
    carafe_fwd<<<grid, 256, 0, stream>>>(x, km, out);
}